// Round 4
// baseline (329.436 us; speedup 1.0000x reference)
//
#include <hip/hip_runtime.h>
#include <hip/hip_bf16.h>
#include <math.h>

#define NB 8          // batch
#define NN 1024       // nodes
#define NI 64         // input feat
#define EHC 4         // E*H
#define ND 128        // hidden
#define NO 64         // outputs
#define FIN1 512      // E*H*D
#define BN 8192       // B*N

typedef __attribute__((ext_vector_type(8))) short short8;
typedef __attribute__((ext_vector_type(4))) float f32x4;

__device__ __forceinline__ unsigned short f2bf(float f) {
    union { float f; unsigned u; } v; v.f = f;
    unsigned r = v.u + 0x7FFF + ((v.u >> 16) & 1);
    return (unsigned short)(r >> 16);
}
__device__ __forceinline__ float bf2f(unsigned short h) {
    union { unsigned u; float f; } v; v.u = ((unsigned)h) << 16;
    return v.f;
}

// ---------------- prep: transpose W0,W1 -> bf16 WT[eh][d][k] ----------------
__global__ void prepTk(const float* __restrict__ W0, const float* __restrict__ W1,
                       unsigned short* __restrict__ W0T, unsigned short* __restrict__ W1T) {
    int idx = blockIdx.x * 256 + threadIdx.x;
    if (idx < EHC * ND * ND) {
        int eh = idx >> 14, d = (idx >> 7) & 127, k = idx & 127;
        W0T[idx] = f2bf(W0[((size_t)(eh * ND + k)) * ND + d]);
    }
    int idx1 = idx - EHC * ND * ND;
    if (idx1 >= 0 && idx1 < EHC * ND * FIN1) {
        int eh = idx1 >> 16;
        int r = idx1 & 65535;
        int d = r >> 9, k = r & 511;
        W1T[idx1] = f2bf(W1[((size_t)(eh * FIN1 + k)) * ND + d]);
    }
}

// ---------------- embed: state0 = relu(nodes @ Wemb + bemb), bf16 out ----------------
__global__ __launch_bounds__(256) void embedk(const float* __restrict__ nodes,
                                              const float* __restrict__ Wemb,
                                              const float* __restrict__ bemb,
                                              unsigned short* __restrict__ state0) {
    int row0 = blockIdx.x * 16;
    int t = threadIdx.x;
    __shared__ float wL[NI * ND];
    __shared__ float nL[16 * NI];
    for (int idx = t; idx < NI * ND; idx += 256) wL[idx] = Wemb[idx];
    for (int idx = t; idx < 16 * NI; idx += 256) nL[idx] = nodes[(size_t)row0 * NI + idx];
    __syncthreads();
    int d = t & 127, rh = t >> 7;
    float b0 = bemb[d];
    float acc[8];
#pragma unroll
    for (int r = 0; r < 8; ++r) acc[r] = b0;
#pragma unroll 8
    for (int k = 0; k < NI; ++k) {
        float w = wL[k * ND + d];
#pragma unroll
        for (int r = 0; r < 8; ++r) acc[r] += nL[(rh * 8 + r) * NI + k] * w;
    }
#pragma unroll
    for (int r = 0; r < 8; ++r)
        state0[(size_t)(row0 + rh * 8 + r) * ND + d] = f2bf(fmaxf(acc[r], 0.f));
}

// ---------------- MFMA filter GEMM (M-tile 32) + fused s1/s2 epilogue ----------------
template <int FIN>
__global__ __launch_bounds__(256, 4) void whgemmk(const unsigned short* __restrict__ state,
                                                  const unsigned short* __restrict__ WT,
                                                  unsigned short* __restrict__ WhT,
                                                  const float* __restrict__ a1w,
                                                  const float* __restrict__ a1b,
                                                  const float* __restrict__ a2w,
                                                  const float* __restrict__ a2b,
                                                  float* __restrict__ s1,
                                                  float* __restrict__ s2) {
    int eh = blockIdx.y;
    int row0 = blockIdx.x * 32;
    int t = threadIdx.x;
    int w = t >> 6, lane = t & 63;
    int m = lane & 15, quad = lane >> 4;

    f32x4 acc[2][2];
#pragma unroll
    for (int mt = 0; mt < 2; ++mt)
#pragma unroll
        for (int nt = 0; nt < 2; ++nt) acc[mt][nt] = (f32x4){0.f, 0.f, 0.f, 0.f};

    const unsigned short* Ab = state + (size_t)(row0 + m) * FIN + quad * 8;
    const unsigned short* Bb = WT + ((size_t)eh * ND + w * 32 + m) * FIN + quad * 8;
#pragma unroll
    for (int k0 = 0; k0 < FIN; k0 += 32) {
        short8 a[2], b[2];
#pragma unroll
        for (int mt = 0; mt < 2; ++mt)
            a[mt] = *(const short8*)(Ab + (size_t)mt * 16 * FIN + k0);
#pragma unroll
        for (int nt = 0; nt < 2; ++nt)
            b[nt] = *(const short8*)(Bb + (size_t)nt * 16 * FIN + k0);
#pragma unroll
        for (int mt = 0; mt < 2; ++mt)
#pragma unroll
            for (int nt = 0; nt < 2; ++nt)
                acc[mt][nt] =
                    __builtin_amdgcn_mfma_f32_16x16x32_bf16(a[mt], b[nt], acc[mt][nt], 0, 0, 0);
    }
    int b_ = row0 >> 10, i0b = row0 & 1023;
    int ehb = eh * NB + b_;
    // store WhT: lane&15 = d-local, quad*4+r = i-local
#pragma unroll
    for (int mt = 0; mt < 2; ++mt)
#pragma unroll
        for (int nt = 0; nt < 2; ++nt) {
            int d = w * 32 + nt * 16 + m;
            int i = i0b + mt * 16 + quad * 4;
            union { unsigned short us[4]; unsigned long long u64; } pk;
#pragma unroll
            for (int r = 0; r < 4; ++r) pk.us[r] = f2bf(acc[mt][nt][r]);
            *(unsigned long long*)(WhT + (((size_t)ehb) * ND + d) * NN + i) = pk.u64;
        }
    // fused s1/s2: s1[i] = sum_d Wh[i,d]*a1w[d] (reduce over m within wave, then over w)
    float w1a = a1w[eh * ND + w * 32 + m], w1b = a1w[eh * ND + w * 32 + 16 + m];
    float w2a = a2w[eh * ND + w * 32 + m], w2b = a2w[eh * ND + w * 32 + 16 + m];
    float p1[2][4], p2[2][4];
#pragma unroll
    for (int mt = 0; mt < 2; ++mt)
#pragma unroll
        for (int r = 0; r < 4; ++r) {
            p1[mt][r] = acc[mt][0][r] * w1a + acc[mt][1][r] * w1b;
            p2[mt][r] = acc[mt][0][r] * w2a + acc[mt][1][r] * w2b;
        }
#pragma unroll
    for (int off = 8; off >= 1; off >>= 1)
#pragma unroll
        for (int mt = 0; mt < 2; ++mt)
#pragma unroll
            for (int r = 0; r < 4; ++r) {
                p1[mt][r] += __shfl_xor(p1[mt][r], off);
                p2[mt][r] += __shfl_xor(p2[mt][r], off);
            }
    __shared__ float sred[2][4][4][8];  // [s][w][quad][mt*4+r]
    if (m == 0) {
#pragma unroll
        for (int mt = 0; mt < 2; ++mt)
#pragma unroll
            for (int r = 0; r < 4; ++r) {
                sred[0][w][quad][mt * 4 + r] = p1[mt][r];
                sred[1][w][quad][mt * 4 + r] = p2[mt][r];
            }
    }
    __syncthreads();
    if (t < 32) {
        int mt = t >> 4, quad2 = (t >> 2) & 3, r = t & 3;
        int c = mt * 4 + r;
        float v = sred[0][0][quad2][c] + sred[0][1][quad2][c] + sred[0][2][quad2][c] +
                  sred[0][3][quad2][c];
        s1[(size_t)ehb * NN + i0b + t] = v + a1b[eh];
    } else if (t < 64) {
        int tl = t - 32;
        int mt = tl >> 4, quad2 = (tl >> 2) & 3, r = tl & 3;
        int c = mt * 4 + r;
        float v = sred[1][0][quad2][c] + sred[1][1][quad2][c] + sred[1][2][quad2][c] +
                  sred[1][3][quad2][c];
        s2[(size_t)ehb * NN + i0b + tl] = v + a2b[eh];
    }
}

// ---------------- column sums (no-max softmax): Spart[ic][eh][b][j], ic=8 ----------------
__global__ __launch_bounds__(256, 4) void colsumk(const float* __restrict__ edges,
                                                  const float* __restrict__ s1,
                                                  const float* __restrict__ s2,
                                                  float* __restrict__ Spart) {
    int jt = blockIdx.x, b = blockIdx.y, ic = blockIdx.z;
    int t = threadIdx.x;
    int jl = t & 63, is = t >> 6;
    int j = jt * 64 + jl;
    __shared__ float s1L[4][128];
    for (int idx = t; idx < 512; idx += 256) {
        int eh = idx >> 7;
        s1L[eh][idx & 127] = s1[((size_t)eh * NB + b) * NN + ic * 128 + (idx & 127)];
    }
    __syncthreads();
    float s2v[4], acc4[4];
#pragma unroll
    for (int eh = 0; eh < 4; ++eh) {
        s2v[eh] = s2[((size_t)eh * NB + b) * NN + j];
        acc4[eh] = 0.f;
    }
    const float2* ep = (const float2*)edges + ((size_t)(b * NN + ic * 128 + is * 32)) * NN + j;
#pragma unroll 4
    for (int ii = 0; ii < 32; ++ii) {
        float2 ev = ep[(size_t)ii * NN];
        int il = is * 32 + ii;
#pragma unroll
        for (int eh = 0; eh < 4; ++eh) {
            float x = s1L[eh][il] + s2v[eh];
            x = x >= 0.f ? x : 0.2f * x;
            float a = x + (eh < 2 ? ev.x : ev.y);
            acc4[eh] += __expf(a);
        }
    }
    __shared__ float red[4][4][64];  // [is][eh][jl]
#pragma unroll
    for (int eh = 0; eh < 4; ++eh) red[is][eh][jl] = acc4[eh];
    __syncthreads();
    if (t < 256) {
        int eho = t >> 6, jlo = t & 63;
        float Sv = red[0][eho][jlo] + red[1][eho][jlo] + red[2][eho][jlo] + red[3][eho][jlo];
        Spart[(((size_t)ic * EHC + eho) * NB + b) * NN + jt * 64 + jlo] = Sv;
    }
}

// ---------------- lnS: reduce Spart -> lnS[ehb][j] ----------------
__global__ __launch_bounds__(256) void s2adjk(const float* __restrict__ Spart,
                                              float* __restrict__ lnS) {
    int gid = blockIdx.x * 256 + threadIdx.x;  // over EHC*BN
    const size_t str = (size_t)EHC * NB * NN;
    float S = 0.f;
#pragma unroll
    for (int ic = 0; ic < 8; ++ic) S += Spart[(size_t)ic * str + gid];
    lnS[gid] = __logf(S);
}

// ---------------- fused msg: C[d][i] = sum_j Wh[j,d]*exp(a_ij - lnS_j), MFMA ------------
__global__ __launch_bounds__(256, 4) void msgk(const float* __restrict__ edges,
                                               const unsigned short* __restrict__ WhT,
                                               const float* __restrict__ s1,
                                               const float* __restrict__ s2,
                                               const float* __restrict__ lnS,
                                               const float* __restrict__ sb,
                                               unsigned short* __restrict__ out0,
                                               float* __restrict__ out1, int mode) {
    int eh = blockIdx.x, itile = blockIdx.y, b = blockIdx.z;
    int e = eh >> 1;
    int i0 = itile * 32;
    int t = threadIdx.x;
    int w = t >> 6, lane = t & 63;
    int n = lane & 15, quad = lane >> 4;
    int jl = t & 63, ib = t >> 6;  // P-compute: 8 rows x 1 col per thread

    __shared__ float2 stL[NN];               // {s2, lnS} per j
    __shared__ unsigned short pA[2][32 * 72];

    int base = (eh * NB + b) * NN;
    for (int idx = t; idx < NN; idx += 256)
        stL[idx] = make_float2(s2[base + idx], lnS[base + idx]);
    float s1r[8];
    {
        const f32x4* sp = (const f32x4*)(s1 + base + i0 + ib * 8);
        f32x4 v0 = sp[0], v1 = sp[1];
#pragma unroll
        for (int r = 0; r < 4; ++r) { s1r[r] = v0[r]; s1r[r + 4] = v1[r]; }
    }

    f32x4 acc[2][2];
#pragma unroll
    for (int mt = 0; mt < 2; ++mt)
#pragma unroll
        for (int nt = 0; nt < 2; ++nt) acc[mt][nt] = (f32x4){0.f, 0.f, 0.f, 0.f};

    const unsigned short* Ab = WhT + ((size_t)base * ND + (size_t)(w * 32 + n) * NN) + quad * 8;
    const float2* ep = (const float2*)edges + (size_t)(b * NN + i0 + ib * 8) * NN + jl;
    __syncthreads();  // stL ready

    float2 evA[8], evB[8];
    short8 aA[4], aB[4];

    auto loadE = [&](float2* ev, int j0) {
#pragma unroll
        for (int q = 0; q < 8; ++q) ev[q] = ep[(size_t)q * NN + j0];
    };
    auto loadA = [&](short8* av, int j0) {
#pragma unroll
        for (int mt = 0; mt < 2; ++mt)
#pragma unroll
            for (int kt = 0; kt < 2; ++kt)
                av[mt * 2 + kt] = *(const short8*)(Ab + (size_t)mt * 16 * NN + kt * 32 + j0);
    };
    auto pstep = [&](const float2* ev, const short8* av, int j0, int buf) {
        float2 st = stL[j0 + jl];
#pragma unroll
        for (int q = 0; q < 8; ++q) {
            float edge = e ? ev[q].y : ev[q].x;
            float x = s1r[q] + st.x;
            x = x >= 0.f ? x : 0.2f * x;
            pA[buf][(ib * 8 + q) * 72 + jl] = f2bf(__expf(x + edge - st.y));
        }
        __syncthreads();
        short8 bv[2][2];
#pragma unroll
        for (int nt = 0; nt < 2; ++nt)
#pragma unroll
            for (int kt = 0; kt < 2; ++kt)
                bv[nt][kt] = *(const short8*)&pA[buf][(nt * 16 + n) * 72 + kt * 32 + quad * 8];
#pragma unroll
        for (int kt = 0; kt < 2; ++kt)
#pragma unroll
            for (int mt = 0; mt < 2; ++mt)
#pragma unroll
                for (int nt = 0; nt < 2; ++nt)
                    acc[mt][nt] = __builtin_amdgcn_mfma_f32_16x16x32_bf16(
                        av[mt * 2 + kt], bv[nt][kt], acc[mt][nt], 0, 0, 0);
    };

    loadE(evA, 0);
    loadA(aA, 0);
    for (int sp2 = 0; sp2 < 8; ++sp2) {
        int j0 = sp2 * 128;
        loadE(evB, j0 + 64);
        loadA(aB, j0 + 64);
        pstep(evA, aA, j0, 0);
        if (sp2 < 7) {
            loadE(evA, j0 + 128);
            loadA(aA, j0 + 128);
        }
        pstep(evB, aB, j0 + 64, 1);
    }

    // epilogue: C row(quad*4+r)=d, col(lane&15)=i-local
#pragma unroll
    for (int mt = 0; mt < 2; ++mt) {
        int d0 = w * 32 + mt * 16 + quad * 4;
        f32x4 sbv = *(const f32x4*)&sb[eh * ND + d0];
#pragma unroll
        for (int nt = 0; nt < 2; ++nt) {
            int i = i0 + nt * 16 + n;
            if (mode == 0) {
                union { unsigned short us[4]; unsigned long long u64; } pk;
#pragma unroll
                for (int r = 0; r < 4; ++r) pk.us[r] = f2bf(acc[mt][nt][r] + sbv[r]);
                *(unsigned long long*)(out0 + (size_t)(b * NN + i) * FIN1 + eh * ND + d0) =
                    pk.u64;
            } else {
                f32x4 vv;
#pragma unroll
                for (int r = 0; r < 4; ++r) {
                    float v = acc[mt][nt][r] + sbv[r];
                    vv[r] = v > 0.f ? v : expm1f(v);
                }
                *(f32x4*)(out1 + ((size_t)(eh * NB + b) * NN + i) * ND + d0) = vv;
            }
        }
    }
}

// ---------------- final: out = mean_eh(m1) @ Wout + bout (fused) ----------------
__global__ __launch_bounds__(256) void finalk(const float* __restrict__ m1,
                                              const float* __restrict__ Wout,
                                              const float* __restrict__ bout,
                                              float* __restrict__ out) {
    int row0 = blockIdx.x * 16;
    int t = threadIdx.x;
    __shared__ float sF[16 * ND];
    __shared__ float wL[ND * NO];
    const size_t str = (size_t)BN * ND;
    for (int idx = t; idx < 16 * ND; idx += 256) {
        size_t r = (size_t)row0 * ND + idx;
        sF[idx] = 0.25f * (m1[r] + m1[r + str] + m1[r + 2 * str] + m1[r + 3 * str]);
    }
    for (int idx = t; idx < ND * NO; idx += 256) wL[idx] = Wout[idx];
    __syncthreads();
    int o = t & 63;
    int rr = t >> 6;
    float bo = bout[o];
#pragma unroll
    for (int q = 0; q < 4; ++q) {
        int r = rr * 4 + q;
        float acc = 0.f;
#pragma unroll 4
        for (int d = 0; d < ND; ++d) acc += sF[r * ND + d] * wL[d * NO + o];
        out[(size_t)(row0 + r) * NO + o] = acc + bo;
    }
}

extern "C" void kernel_launch(void* const* d_in, const int* in_sizes, int n_in,
                              void* d_out, int out_size, void* d_ws, size_t ws_size,
                              hipStream_t stream) {
    const float* nodes = (const float*)d_in[0];
    const float* edges = (const float*)d_in[1];
    const float* Wemb = (const float*)d_in[2];
    const float* bemb = (const float*)d_in[3];
    const float* W0 = (const float*)d_in[4];
    const float* A1w0 = (const float*)d_in[5];
    const float* A1b0 = (const float*)d_in[6];
    const float* A2w0 = (const float*)d_in[7];
    const float* A2b0 = (const float*)d_in[8];
    const float* SB0 = (const float*)d_in[9];
    const float* W1 = (const float*)d_in[10];
    const float* A1w1 = (const float*)d_in[11];
    const float* A1b1 = (const float*)d_in[12];
    const float* A2w1 = (const float*)d_in[13];
    const float* A2b1 = (const float*)d_in[14];
    const float* SB1 = (const float*)d_in[15];
    const float* Wout = (const float*)d_in[16];
    const float* bout = (const float*)d_in[17];
    float* out = (float*)d_out;

    char* p = (char*)d_ws;
    auto alloc = [&](size_t bytes) {
        char* r = p;
        p += (bytes + 255) & ~(size_t)255;
        return r;
    };
    unsigned short* state0 = (unsigned short*)alloc((size_t)BN * ND * 2);
    unsigned short* W0T = (unsigned short*)alloc((size_t)EHC * ND * ND * 2);
    unsigned short* W1T = (unsigned short*)alloc((size_t)EHC * ND * FIN1 * 2);
    unsigned short* WhT = (unsigned short*)alloc((size_t)EHC * BN * ND * 2);
    unsigned short* state1 = (unsigned short*)alloc((size_t)BN * FIN1 * 2);
    float* s1b = (float*)alloc((size_t)EHC * BN * 4);
    float* s2b = (float*)alloc((size_t)EHC * BN * 4);
    float* Spart = (float*)alloc((size_t)8 * EHC * BN * 4);
    float* lnSb = (float*)alloc((size_t)EHC * BN * 4);
    float* m1 = (float*)alloc((size_t)EHC * BN * ND * 4);

    prepTk<<<1280, 256, 0, stream>>>(W0, W1, W0T, W1T);
    embedk<<<BN / 16, 256, 0, stream>>>(nodes, Wemb, bemb, state0);
    // layer 0
    whgemmk<ND><<<dim3(BN / 32, EHC), 256, 0, stream>>>(state0, W0T, WhT, A1w0, A1b0, A2w0,
                                                        A2b0, s1b, s2b);
    colsumk<<<dim3(NN / 64, NB, 8), 256, 0, stream>>>(edges, s1b, s2b, Spart);
    s2adjk<<<EHC * BN / 256, 256, 0, stream>>>(Spart, lnSb);
    msgk<<<dim3(EHC, NN / 32, NB), 256, 0, stream>>>(edges, WhT, s1b, s2b, lnSb, SB0,
                                                     state1, m1, 0);
    // layer 1
    whgemmk<FIN1><<<dim3(BN / 32, EHC), 256, 0, stream>>>(state1, W1T, WhT, A1w1, A1b1, A2w1,
                                                          A2b1, s1b, s2b);
    colsumk<<<dim3(NN / 64, NB, 8), 256, 0, stream>>>(edges, s1b, s2b, Spart);
    s2adjk<<<EHC * BN / 256, 256, 0, stream>>>(Spart, lnSb);
    msgk<<<dim3(EHC, NN / 32, NB), 256, 0, stream>>>(edges, WhT, s1b, s2b, lnSb, SB1,
                                                     state1, m1, 1);
    // head
    finalk<<<BN / 16, 256, 0, stream>>>(m1, Wout, bout, out);
}

// Round 5
// 285.433 us; speedup vs baseline: 1.1542x; 1.1542x over previous
//
#include <hip/hip_runtime.h>
#include <hip/hip_bf16.h>
#include <math.h>

#define NB 8          // batch
#define NN 1024       // nodes
#define NI 64         // input feat
#define EHC 4         // E*H
#define ND 128        // hidden
#define NO 64         // outputs
#define FIN1 512      // E*H*D
#define BN 8192       // B*N

typedef __attribute__((ext_vector_type(8))) short short8;
typedef __attribute__((ext_vector_type(4))) float f32x4;

__device__ __forceinline__ unsigned short f2bf(float f) {
    union { float f; unsigned u; } v; v.f = f;
    unsigned r = v.u + 0x7FFF + ((v.u >> 16) & 1);
    return (unsigned short)(r >> 16);
}

// ---------------- prep: W0,W1 -> bf16 WT[eh][d][k]; Wemb -> WembT[d][k] ----------------
__global__ void prepTk(const float* __restrict__ W0, const float* __restrict__ W1,
                       const float* __restrict__ Wemb, unsigned short* __restrict__ W0T,
                       unsigned short* __restrict__ W1T, unsigned short* __restrict__ WembT) {
    int idx = blockIdx.x * 256 + threadIdx.x;
    if (idx < EHC * ND * ND) {
        int eh = idx >> 14, d = (idx >> 7) & 127, k = idx & 127;
        W0T[idx] = f2bf(W0[((size_t)(eh * ND + k)) * ND + d]);
    }
    int idx1 = idx - EHC * ND * ND;
    if (idx1 >= 0 && idx1 < EHC * ND * FIN1) {
        int eh = idx1 >> 16;
        int r = idx1 & 65535;
        int d = r >> 9, k = r & 511;
        W1T[idx1] = f2bf(W1[((size_t)(eh * FIN1 + k)) * ND + d]);
    }
    int idx2 = idx - (EHC * ND * ND + EHC * ND * FIN1);
    if (idx2 >= 0 && idx2 < ND * NI) {
        int d = idx2 >> 6, k = idx2 & 63;
        WembT[idx2] = f2bf(Wemb[k * ND + d]);
    }
}

// ---------------- fused embed + layer-0 filter GEMM + s1/s2 epilogue ----------------
__global__ __launch_bounds__(256, 4) void embwh0k(
    const float* __restrict__ nodes, const unsigned short* __restrict__ WembT,
    const float* __restrict__ bemb, const unsigned short* __restrict__ W0T,
    unsigned short* __restrict__ WhT, const float* __restrict__ a1w,
    const float* __restrict__ a1b, const float* __restrict__ a2w,
    const float* __restrict__ a2b, float* __restrict__ s1, float* __restrict__ s2) {
    int id = blockIdx.x;
    int g = id & 7, s_ = id >> 3;
    int eh = s_ & 3;
    int row0 = ((s_ >> 2) * 8 + g) * 32;   // 4 eh-blocks share row tile, same XCD slot
    int t = threadIdx.x;
    int w = t >> 6, lane = t & 63;
    int m = lane & 15, quad = lane >> 4;

    __shared__ unsigned short stateL[32 * 136];  // 32 rows x 128 d, pad to 136

    // ---- embed via MFMA: state = relu(nodes @ Wemb + bemb) ----
    f32x4 accE[2][2];
#pragma unroll
    for (int mt = 0; mt < 2; ++mt)
#pragma unroll
        for (int nt = 0; nt < 2; ++nt) accE[mt][nt] = (f32x4){0.f, 0.f, 0.f, 0.f};
#pragma unroll
    for (int kt = 0; kt < 2; ++kt) {
        short8 aE[2], bE[2];
#pragma unroll
        for (int mt = 0; mt < 2; ++mt) {
            const float* np = nodes + (size_t)(row0 + mt * 16 + m) * NI + kt * 32 + quad * 8;
            f32x4 v0 = *(const f32x4*)np;
            f32x4 v1 = *(const f32x4*)(np + 4);
            union { unsigned short us[8]; short8 s8; } pk;
#pragma unroll
            for (int r = 0; r < 4; ++r) {
                pk.us[r] = f2bf(v0[r]);
                pk.us[r + 4] = f2bf(v1[r]);
            }
            aE[mt] = pk.s8;
        }
#pragma unroll
        for (int nt = 0; nt < 2; ++nt)
            bE[nt] = *(const short8*)(WembT + (w * 32 + nt * 16 + m) * NI + kt * 32 + quad * 8);
#pragma unroll
        for (int mt = 0; mt < 2; ++mt)
#pragma unroll
            for (int nt = 0; nt < 2; ++nt)
                accE[mt][nt] =
                    __builtin_amdgcn_mfma_f32_16x16x32_bf16(aE[mt], bE[nt], accE[mt][nt], 0, 0, 0);
    }
#pragma unroll
    for (int mt = 0; mt < 2; ++mt)
#pragma unroll
        for (int nt = 0; nt < 2; ++nt) {
            int d = w * 32 + nt * 16 + m;
            float bb = bemb[d];
#pragma unroll
            for (int r = 0; r < 4; ++r) {
                float v = fmaxf(accE[mt][nt][r] + bb, 0.f);
                stateL[(mt * 16 + quad * 4 + r) * 136 + d] = f2bf(v);
            }
        }
    __syncthreads();

    // ---- main GEMM: Wh = state @ W0[eh], K=128, A from LDS ----
    f32x4 acc[2][2];
#pragma unroll
    for (int mt = 0; mt < 2; ++mt)
#pragma unroll
        for (int nt = 0; nt < 2; ++nt) acc[mt][nt] = (f32x4){0.f, 0.f, 0.f, 0.f};
#pragma unroll
    for (int k0 = 0; k0 < ND; k0 += 32) {
        short8 a[2], b[2];
#pragma unroll
        for (int mt = 0; mt < 2; ++mt)
            a[mt] = *(const short8*)&stateL[(mt * 16 + m) * 136 + k0 + quad * 8];
#pragma unroll
        for (int nt = 0; nt < 2; ++nt)
            b[nt] = *(const short8*)(W0T + ((size_t)(eh * ND + w * 32 + nt * 16 + m)) * ND +
                                     k0 + quad * 8);
#pragma unroll
        for (int mt = 0; mt < 2; ++mt)
#pragma unroll
            for (int nt = 0; nt < 2; ++nt)
                acc[mt][nt] =
                    __builtin_amdgcn_mfma_f32_16x16x32_bf16(a[mt], b[nt], acc[mt][nt], 0, 0, 0);
    }

    // ---- epilogue: store WhT + fused s1/s2 ----
    int b_ = row0 >> 10, i0b = row0 & 1023;
    int ehb = eh * NB + b_;
#pragma unroll
    for (int mt = 0; mt < 2; ++mt)
#pragma unroll
        for (int nt = 0; nt < 2; ++nt) {
            int d = w * 32 + nt * 16 + m;
            int i = i0b + mt * 16 + quad * 4;
            union { unsigned short us[4]; unsigned long long u64; } pk;
#pragma unroll
            for (int r = 0; r < 4; ++r) pk.us[r] = f2bf(acc[mt][nt][r]);
            *(unsigned long long*)(WhT + (((size_t)ehb) * ND + d) * NN + i) = pk.u64;
        }
    float w1a = a1w[eh * ND + w * 32 + m], w1b = a1w[eh * ND + w * 32 + 16 + m];
    float w2a = a2w[eh * ND + w * 32 + m], w2b = a2w[eh * ND + w * 32 + 16 + m];
    float p1[2][4], p2[2][4];
#pragma unroll
    for (int mt = 0; mt < 2; ++mt)
#pragma unroll
        for (int r = 0; r < 4; ++r) {
            p1[mt][r] = acc[mt][0][r] * w1a + acc[mt][1][r] * w1b;
            p2[mt][r] = acc[mt][0][r] * w2a + acc[mt][1][r] * w2b;
        }
#pragma unroll
    for (int off = 8; off >= 1; off >>= 1)
#pragma unroll
        for (int mt = 0; mt < 2; ++mt)
#pragma unroll
            for (int r = 0; r < 4; ++r) {
                p1[mt][r] += __shfl_xor(p1[mt][r], off);
                p2[mt][r] += __shfl_xor(p2[mt][r], off);
            }
    __shared__ float sred[2][4][4][8];
    if (m == 0) {
#pragma unroll
        for (int mt = 0; mt < 2; ++mt)
#pragma unroll
            for (int r = 0; r < 4; ++r) {
                sred[0][w][quad][mt * 4 + r] = p1[mt][r];
                sred[1][w][quad][mt * 4 + r] = p2[mt][r];
            }
    }
    __syncthreads();
    if (t < 32) {
        int mt = t >> 4, quad2 = (t >> 2) & 3, r = t & 3;
        int c = mt * 4 + r;
        float v = sred[0][0][quad2][c] + sred[0][1][quad2][c] + sred[0][2][quad2][c] +
                  sred[0][3][quad2][c];
        s1[(size_t)ehb * NN + i0b + t] = v + a1b[eh];
    } else if (t < 64) {
        int tl = t - 32;
        int mt = tl >> 4, quad2 = (tl >> 2) & 3, r = tl & 3;
        int c = mt * 4 + r;
        float v = sred[1][0][quad2][c] + sred[1][1][quad2][c] + sred[1][2][quad2][c] +
                  sred[1][3][quad2][c];
        s2[(size_t)ehb * NN + i0b + tl] = v + a2b[eh];
    }
}

// ---------------- layer-1 filter GEMM (K=512) + s1/s2 epilogue, XCD-swizzled ----------
__global__ __launch_bounds__(256, 4) void whgemm1k(
    const unsigned short* __restrict__ state, const unsigned short* __restrict__ WT,
    unsigned short* __restrict__ WhT, const float* __restrict__ a1w,
    const float* __restrict__ a1b, const float* __restrict__ a2w,
    const float* __restrict__ a2b, float* __restrict__ s1, float* __restrict__ s2) {
    int id = blockIdx.x;
    int g = id & 7, s_ = id >> 3;
    int eh = s_ & 3;
    int row0 = ((s_ >> 2) * 8 + g) * 32;
    int t = threadIdx.x;
    int w = t >> 6, lane = t & 63;
    int m = lane & 15, quad = lane >> 4;

    f32x4 acc[2][2];
#pragma unroll
    for (int mt = 0; mt < 2; ++mt)
#pragma unroll
        for (int nt = 0; nt < 2; ++nt) acc[mt][nt] = (f32x4){0.f, 0.f, 0.f, 0.f};

    const unsigned short* Ab = state + (size_t)(row0 + m) * FIN1 + quad * 8;
    const unsigned short* Bb = WT + ((size_t)eh * ND + w * 32 + m) * FIN1 + quad * 8;
#pragma unroll 4
    for (int k0 = 0; k0 < FIN1; k0 += 32) {
        short8 a[2], b[2];
#pragma unroll
        for (int mt = 0; mt < 2; ++mt)
            a[mt] = *(const short8*)(Ab + (size_t)mt * 16 * FIN1 + k0);
#pragma unroll
        for (int nt = 0; nt < 2; ++nt)
            b[nt] = *(const short8*)(Bb + (size_t)nt * 16 * FIN1 + k0);
#pragma unroll
        for (int mt = 0; mt < 2; ++mt)
#pragma unroll
            for (int nt = 0; nt < 2; ++nt)
                acc[mt][nt] =
                    __builtin_amdgcn_mfma_f32_16x16x32_bf16(a[mt], b[nt], acc[mt][nt], 0, 0, 0);
    }
    int b_ = row0 >> 10, i0b = row0 & 1023;
    int ehb = eh * NB + b_;
#pragma unroll
    for (int mt = 0; mt < 2; ++mt)
#pragma unroll
        for (int nt = 0; nt < 2; ++nt) {
            int d = w * 32 + nt * 16 + m;
            int i = i0b + mt * 16 + quad * 4;
            union { unsigned short us[4]; unsigned long long u64; } pk;
#pragma unroll
            for (int r = 0; r < 4; ++r) pk.us[r] = f2bf(acc[mt][nt][r]);
            *(unsigned long long*)(WhT + (((size_t)ehb) * ND + d) * NN + i) = pk.u64;
        }
    float w1a = a1w[eh * ND + w * 32 + m], w1b = a1w[eh * ND + w * 32 + 16 + m];
    float w2a = a2w[eh * ND + w * 32 + m], w2b = a2w[eh * ND + w * 32 + 16 + m];
    float p1[2][4], p2[2][4];
#pragma unroll
    for (int mt = 0; mt < 2; ++mt)
#pragma unroll
        for (int r = 0; r < 4; ++r) {
            p1[mt][r] = acc[mt][0][r] * w1a + acc[mt][1][r] * w1b;
            p2[mt][r] = acc[mt][0][r] * w2a + acc[mt][1][r] * w2b;
        }
#pragma unroll
    for (int off = 8; off >= 1; off >>= 1)
#pragma unroll
        for (int mt = 0; mt < 2; ++mt)
#pragma unroll
            for (int r = 0; r < 4; ++r) {
                p1[mt][r] += __shfl_xor(p1[mt][r], off);
                p2[mt][r] += __shfl_xor(p2[mt][r], off);
            }
    __shared__ float sred[2][4][4][8];
    if (m == 0) {
#pragma unroll
        for (int mt = 0; mt < 2; ++mt)
#pragma unroll
            for (int r = 0; r < 4; ++r) {
                sred[0][w][quad][mt * 4 + r] = p1[mt][r];
                sred[1][w][quad][mt * 4 + r] = p2[mt][r];
            }
    }
    __syncthreads();
    if (t < 32) {
        int mt = t >> 4, quad2 = (t >> 2) & 3, r = t & 3;
        int c = mt * 4 + r;
        float v = sred[0][0][quad2][c] + sred[0][1][quad2][c] + sred[0][2][quad2][c] +
                  sred[0][3][quad2][c];
        s1[(size_t)ehb * NN + i0b + t] = v + a1b[eh];
    } else if (t < 64) {
        int tl = t - 32;
        int mt = tl >> 4, quad2 = (tl >> 2) & 3, r = tl & 3;
        int c = mt * 4 + r;
        float v = sred[1][0][quad2][c] + sred[1][1][quad2][c] + sred[1][2][quad2][c] +
                  sred[1][3][quad2][c];
        s2[(size_t)ehb * NN + i0b + tl] = v + a2b[eh];
    }
}

// ---------------- column sums (no-max softmax): Spart[ic][eh][b][j], ic=8 ----------------
__global__ __launch_bounds__(256, 4) void colsumk(const float* __restrict__ edges,
                                                  const float* __restrict__ s1,
                                                  const float* __restrict__ s2,
                                                  float* __restrict__ Spart) {
    int jt = blockIdx.x, b = blockIdx.y, ic = blockIdx.z;
    int t = threadIdx.x;
    int jl = t & 63, is = t >> 6;
    int j = jt * 64 + jl;
    __shared__ float s1L[4][128];
    for (int idx = t; idx < 512; idx += 256) {
        int eh = idx >> 7;
        s1L[eh][idx & 127] = s1[((size_t)eh * NB + b) * NN + ic * 128 + (idx & 127)];
    }
    __syncthreads();
    float s2v[4], acc4[4];
#pragma unroll
    for (int eh = 0; eh < 4; ++eh) {
        s2v[eh] = s2[((size_t)eh * NB + b) * NN + j];
        acc4[eh] = 0.f;
    }
    const float2* ep = (const float2*)edges + ((size_t)(b * NN + ic * 128 + is * 32)) * NN + j;
#pragma unroll 8
    for (int ii = 0; ii < 32; ++ii) {
        float2 ev = ep[(size_t)ii * NN];
        int il = is * 32 + ii;
#pragma unroll
        for (int eh = 0; eh < 4; ++eh) {
            float x = s1L[eh][il] + s2v[eh];
            x = x >= 0.f ? x : 0.2f * x;
            float a = x + (eh < 2 ? ev.x : ev.y);
            acc4[eh] += __expf(a);
        }
    }
    __shared__ float red[4][4][64];
#pragma unroll
    for (int eh = 0; eh < 4; ++eh) red[is][eh][jl] = acc4[eh];
    __syncthreads();
    if (t < 256) {
        int eho = t >> 6, jlo = t & 63;
        float Sv = red[0][eho][jlo] + red[1][eho][jlo] + red[2][eho][jlo] + red[3][eho][jlo];
        Spart[(((size_t)ic * EHC + eho) * NB + b) * NN + jt * 64 + jlo] = Sv;
    }
}

// ---------------- fused msg: C[d][i] = sum_j Wh[j,d]*exp(a_ij - lnS_j), MFMA ------------
__global__ __launch_bounds__(256, 4) void msgk(const float* __restrict__ edges,
                                               const unsigned short* __restrict__ WhT,
                                               const float* __restrict__ s1,
                                               const float* __restrict__ s2,
                                               const float* __restrict__ Spart,
                                               const float* __restrict__ sb,
                                               unsigned short* __restrict__ out0,
                                               float* __restrict__ out1, int mode) {
    int id = blockIdx.x;
    int b = id & 7;                 // XCD slot: 4 eh-blocks of same (itile,b) share L2
    int s_ = id >> 3;
    int eh = s_ & 3;
    int itile = s_ >> 2;
    int e = eh >> 1;
    int i0 = itile * 64;
    int t = threadIdx.x;
    int w = t >> 6, lane = t & 63;
    int n = lane & 15, quad = lane >> 4;
    int jl = t & 63, ib = w;        // P-compute: 16 rows x 1 col per thread

    __shared__ float2 stL[NN];                  // {s2, lnS} per j
    __shared__ unsigned short pA[2][64 * 72];

    int base = (eh * NB + b) * NN;
    const size_t pstr = (size_t)EHC * NB * NN;
    for (int jj = t; jj < NN; jj += 256) {
        float S = 0.f;
#pragma unroll
        for (int ic = 0; ic < 8; ++ic) S += Spart[(size_t)ic * pstr + base + jj];
        stL[jj] = make_float2(s2[base + jj], __logf(S));
    }
    float s1r[16];
    {
        const f32x4* sp = (const f32x4*)(s1 + base + i0 + ib * 16);
#pragma unroll
        for (int q4 = 0; q4 < 4; ++q4) {
            f32x4 v = sp[q4];
#pragma unroll
            for (int r = 0; r < 4; ++r) s1r[q4 * 4 + r] = v[r];
        }
    }

    f32x4 acc[2][4];
#pragma unroll
    for (int mt = 0; mt < 2; ++mt)
#pragma unroll
        for (int nt = 0; nt < 4; ++nt) acc[mt][nt] = (f32x4){0.f, 0.f, 0.f, 0.f};

    const unsigned short* Ab =
        WhT + ((size_t)base * ND + (size_t)(w * 32 + n) * NN) + quad * 8;
    const float2* ep = (const float2*)edges + (size_t)(b * NN + i0 + ib * 16) * NN + jl;
    __syncthreads();  // stL ready

    for (int st16 = 0; st16 < 16; ++st16) {
        int j0 = st16 * 64;
        int buf = st16 & 1;
        float2 stj = stL[j0 + jl];
#pragma unroll
        for (int q = 0; q < 16; ++q) {
            float2 ev = ep[(size_t)q * NN + j0];
            float edge = e ? ev.y : ev.x;
            float x = s1r[q] + stj.x;
            x = x >= 0.f ? x : 0.2f * x;
            pA[buf][(ib * 16 + q) * 72 + jl] = f2bf(__expf(x + edge - stj.y));
        }
        __syncthreads();
#pragma unroll
        for (int kt = 0; kt < 2; ++kt) {
            short8 av[2], bv[4];
#pragma unroll
            for (int mt = 0; mt < 2; ++mt)
                av[mt] = *(const short8*)(Ab + (size_t)mt * 16 * NN + kt * 32 + j0);
#pragma unroll
            for (int nt = 0; nt < 4; ++nt)
                bv[nt] = *(const short8*)&pA[buf][(nt * 16 + n) * 72 + kt * 32 + quad * 8];
#pragma unroll
            for (int mt = 0; mt < 2; ++mt)
#pragma unroll
                for (int nt = 0; nt < 4; ++nt)
                    acc[mt][nt] = __builtin_amdgcn_mfma_f32_16x16x32_bf16(av[mt], bv[nt],
                                                                          acc[mt][nt], 0, 0, 0);
        }
    }

    // epilogue: C row(quad*4+r)=d, col(lane&15)=i-local
#pragma unroll
    for (int mt = 0; mt < 2; ++mt) {
        int d0 = w * 32 + mt * 16 + quad * 4;
        f32x4 sbv = *(const f32x4*)&sb[eh * ND + d0];
#pragma unroll
        for (int nt = 0; nt < 4; ++nt) {
            int i = i0 + nt * 16 + n;
            if (mode == 0) {
                union { unsigned short us[4]; unsigned long long u64; } pk;
#pragma unroll
                for (int r = 0; r < 4; ++r) pk.us[r] = f2bf(acc[mt][nt][r] + sbv[r]);
                *(unsigned long long*)(out0 + (size_t)(b * NN + i) * FIN1 + eh * ND + d0) =
                    pk.u64;
            } else {
                f32x4 vv;
#pragma unroll
                for (int r = 0; r < 4; ++r) {
                    float v = acc[mt][nt][r] + sbv[r];
                    vv[r] = v > 0.f ? v : expm1f(v);
                }
                *(f32x4*)(out1 + ((size_t)(eh * NB + b) * NN + i) * ND + d0) = vv;
            }
        }
    }
}

// ---------------- final: out = mean_eh(m1) @ Wout + bout (fused) ----------------
__global__ __launch_bounds__(256) void finalk(const float* __restrict__ m1,
                                              const float* __restrict__ Wout,
                                              const float* __restrict__ bout,
                                              float* __restrict__ out) {
    int row0 = blockIdx.x * 16;
    int t = threadIdx.x;
    __shared__ float sF[16 * ND];
    __shared__ float wL[ND * NO];
    const size_t str = (size_t)BN * ND;
    for (int idx = t; idx < 16 * ND; idx += 256) {
        size_t r = (size_t)row0 * ND + idx;
        sF[idx] = 0.25f * (m1[r] + m1[r + str] + m1[r + 2 * str] + m1[r + 3 * str]);
    }
    for (int idx = t; idx < ND * NO; idx += 256) wL[idx] = Wout[idx];
    __syncthreads();
    int o = t & 63;
    int rr = t >> 6;
    float bo = bout[o];
#pragma unroll
    for (int q = 0; q < 4; ++q) {
        int r = rr * 4 + q;
        float acc = 0.f;
#pragma unroll 4
        for (int d = 0; d < ND; ++d) acc += sF[r * ND + d] * wL[d * NO + o];
        out[(size_t)(row0 + r) * NO + o] = acc + bo;
    }
}

extern "C" void kernel_launch(void* const* d_in, const int* in_sizes, int n_in,
                              void* d_out, int out_size, void* d_ws, size_t ws_size,
                              hipStream_t stream) {
    const float* nodes = (const float*)d_in[0];
    const float* edges = (const float*)d_in[1];
    const float* Wemb = (const float*)d_in[2];
    const float* bemb = (const float*)d_in[3];
    const float* W0 = (const float*)d_in[4];
    const float* A1w0 = (const float*)d_in[5];
    const float* A1b0 = (const float*)d_in[6];
    const float* A2w0 = (const float*)d_in[7];
    const float* A2b0 = (const float*)d_in[8];
    const float* SB0 = (const float*)d_in[9];
    const float* W1 = (const float*)d_in[10];
    const float* A1w1 = (const float*)d_in[11];
    const float* A1b1 = (const float*)d_in[12];
    const float* A2w1 = (const float*)d_in[13];
    const float* A2b1 = (const float*)d_in[14];
    const float* SB1 = (const float*)d_in[15];
    const float* Wout = (const float*)d_in[16];
    const float* bout = (const float*)d_in[17];
    float* out = (float*)d_out;

    char* p = (char*)d_ws;
    auto alloc = [&](size_t bytes) {
        char* r = p;
        p += (bytes + 255) & ~(size_t)255;
        return r;
    };
    unsigned short* W0T = (unsigned short*)alloc((size_t)EHC * ND * ND * 2);
    unsigned short* W1T = (unsigned short*)alloc((size_t)EHC * ND * FIN1 * 2);
    unsigned short* WembT = (unsigned short*)alloc((size_t)ND * NI * 2);
    unsigned short* WhT = (unsigned short*)alloc((size_t)EHC * BN * ND * 2);
    unsigned short* state1 = (unsigned short*)alloc((size_t)BN * FIN1 * 2);
    float* s1b = (float*)alloc((size_t)EHC * BN * 4);
    float* s2b = (float*)alloc((size_t)EHC * BN * 4);
    float* Spart = (float*)alloc((size_t)8 * EHC * BN * 4);
    float* m1 = (float*)alloc((size_t)EHC * BN * ND * 4);

    prepTk<<<1312, 256, 0, stream>>>(W0, W1, Wemb, W0T, W1T, WembT);
    // layer 0 (embed fused into filter GEMM)
    embwh0k<<<1024, 256, 0, stream>>>(nodes, WembT, bemb, W0T, WhT, A1w0, A1b0, A2w0, A2b0,
                                      s1b, s2b);
    colsumk<<<dim3(NN / 64, NB, 8), 256, 0, stream>>>(edges, s1b, s2b, Spart);
    msgk<<<512, 256, 0, stream>>>(edges, WhT, s1b, s2b, Spart, SB0, state1, m1, 0);
    // layer 1
    whgemm1k<<<1024, 256, 0, stream>>>(state1, W1T, WhT, A1w1, A1b1, A2w1, A2b1, s1b, s2b);
    colsumk<<<dim3(NN / 64, NB, 8), 256, 0, stream>>>(edges, s1b, s2b, Spart);
    msgk<<<512, 256, 0, stream>>>(edges, WhT, s1b, s2b, Spart, SB1, state1, m1, 1);
    // head
    finalk<<<BN / 16, 256, 0, stream>>>(m1, Wout, bout, out);
}

// Round 6
// 274.183 us; speedup vs baseline: 1.2015x; 1.0410x over previous
//
#include <hip/hip_runtime.h>
#include <hip/hip_bf16.h>
#include <math.h>

#define NB 8          // batch
#define NN 1024       // nodes
#define NI 64         // input feat
#define EHC 4         // E*H
#define ND 128        // hidden
#define NO 64         // outputs
#define FIN1 512      // E*H*D
#define BN 8192       // B*N

typedef __attribute__((ext_vector_type(8))) short short8;
typedef __attribute__((ext_vector_type(4))) float f32x4;

__device__ __forceinline__ unsigned short f2bf(float f) {
    union { float f; unsigned u; } v; v.f = f;
    unsigned r = v.u + 0x7FFF + ((v.u >> 16) & 1);
    return (unsigned short)(r >> 16);
}

// ---------------- prep: W0,W1 -> bf16 WT[eh][d][k]; Wemb -> WembT[d][k] ----------------
__global__ void prepTk(const float* __restrict__ W0, const float* __restrict__ W1,
                       const float* __restrict__ Wemb, unsigned short* __restrict__ W0T,
                       unsigned short* __restrict__ W1T, unsigned short* __restrict__ WembT) {
    int idx = blockIdx.x * 256 + threadIdx.x;
    if (idx < EHC * ND * ND) {
        int eh = idx >> 14, d = (idx >> 7) & 127, k = idx & 127;
        W0T[idx] = f2bf(W0[((size_t)(eh * ND + k)) * ND + d]);
    }
    int idx1 = idx - EHC * ND * ND;
    if (idx1 >= 0 && idx1 < EHC * ND * FIN1) {
        int eh = idx1 >> 16;
        int r = idx1 & 65535;
        int d = r >> 9, k = r & 511;
        W1T[idx1] = f2bf(W1[((size_t)(eh * FIN1 + k)) * ND + d]);
    }
    int idx2 = idx - (EHC * ND * ND + EHC * ND * FIN1);
    if (idx2 >= 0 && idx2 < ND * NI) {
        int d = idx2 >> 6, k = idx2 & 63;
        WembT[idx2] = f2bf(Wemb[k * ND + d]);
    }
}

// ---------------- fused embed + layer-0 filter GEMM + s1/s2 epilogue ----------------
__global__ __launch_bounds__(256, 4) void embwh0k(
    const float* __restrict__ nodes, const unsigned short* __restrict__ WembT,
    const float* __restrict__ bemb, const unsigned short* __restrict__ W0T,
    unsigned short* __restrict__ WhT, const float* __restrict__ a1w,
    const float* __restrict__ a1b, const float* __restrict__ a2w,
    const float* __restrict__ a2b, float* __restrict__ s1, float* __restrict__ s2) {
    int id = blockIdx.x;
    int g = id & 7, s_ = id >> 3;
    int eh = s_ & 3;
    int row0 = ((s_ >> 2) * 8 + g) * 32;   // 4 eh-blocks share row tile, same XCD slot
    int t = threadIdx.x;
    int w = t >> 6, lane = t & 63;
    int m = lane & 15, quad = lane >> 4;

    __shared__ unsigned short stateL[32 * 136];  // 32 rows x 128 d, pad to 136

    // ---- embed via MFMA: state = relu(nodes @ Wemb + bemb) ----
    f32x4 accE[2][2];
#pragma unroll
    for (int mt = 0; mt < 2; ++mt)
#pragma unroll
        for (int nt = 0; nt < 2; ++nt) accE[mt][nt] = (f32x4){0.f, 0.f, 0.f, 0.f};
#pragma unroll
    for (int kt = 0; kt < 2; ++kt) {
        short8 aE[2], bE[2];
#pragma unroll
        for (int mt = 0; mt < 2; ++mt) {
            const float* np = nodes + (size_t)(row0 + mt * 16 + m) * NI + kt * 32 + quad * 8;
            f32x4 v0 = *(const f32x4*)np;
            f32x4 v1 = *(const f32x4*)(np + 4);
            union { unsigned short us[8]; short8 s8; } pk;
#pragma unroll
            for (int r = 0; r < 4; ++r) {
                pk.us[r] = f2bf(v0[r]);
                pk.us[r + 4] = f2bf(v1[r]);
            }
            aE[mt] = pk.s8;
        }
#pragma unroll
        for (int nt = 0; nt < 2; ++nt)
            bE[nt] = *(const short8*)(WembT + (w * 32 + nt * 16 + m) * NI + kt * 32 + quad * 8);
#pragma unroll
        for (int mt = 0; mt < 2; ++mt)
#pragma unroll
            for (int nt = 0; nt < 2; ++nt)
                accE[mt][nt] =
                    __builtin_amdgcn_mfma_f32_16x16x32_bf16(aE[mt], bE[nt], accE[mt][nt], 0, 0, 0);
    }
#pragma unroll
    for (int mt = 0; mt < 2; ++mt)
#pragma unroll
        for (int nt = 0; nt < 2; ++nt) {
            int d = w * 32 + nt * 16 + m;
            float bb = bemb[d];
#pragma unroll
            for (int r = 0; r < 4; ++r) {
                float v = fmaxf(accE[mt][nt][r] + bb, 0.f);
                stateL[(mt * 16 + quad * 4 + r) * 136 + d] = f2bf(v);
            }
        }
    __syncthreads();

    // ---- main GEMM: Wh = state @ W0[eh], K=128, A from LDS ----
    f32x4 acc[2][2];
#pragma unroll
    for (int mt = 0; mt < 2; ++mt)
#pragma unroll
        for (int nt = 0; nt < 2; ++nt) acc[mt][nt] = (f32x4){0.f, 0.f, 0.f, 0.f};
#pragma unroll
    for (int k0 = 0; k0 < ND; k0 += 32) {
        short8 a[2], b[2];
#pragma unroll
        for (int mt = 0; mt < 2; ++mt)
            a[mt] = *(const short8*)&stateL[(mt * 16 + m) * 136 + k0 + quad * 8];
#pragma unroll
        for (int nt = 0; nt < 2; ++nt)
            b[nt] = *(const short8*)(W0T + ((size_t)(eh * ND + w * 32 + nt * 16 + m)) * ND +
                                     k0 + quad * 8);
#pragma unroll
        for (int mt = 0; mt < 2; ++mt)
#pragma unroll
            for (int nt = 0; nt < 2; ++nt)
                acc[mt][nt] =
                    __builtin_amdgcn_mfma_f32_16x16x32_bf16(a[mt], b[nt], acc[mt][nt], 0, 0, 0);
    }

    // ---- epilogue: store WhT + fused s1/s2 ----
    int b_ = row0 >> 10, i0b = row0 & 1023;
    int ehb = eh * NB + b_;
#pragma unroll
    for (int mt = 0; mt < 2; ++mt)
#pragma unroll
        for (int nt = 0; nt < 2; ++nt) {
            int d = w * 32 + nt * 16 + m;
            int i = i0b + mt * 16 + quad * 4;
            union { unsigned short us[4]; unsigned long long u64; } pk;
#pragma unroll
            for (int r = 0; r < 4; ++r) pk.us[r] = f2bf(acc[mt][nt][r]);
            *(unsigned long long*)(WhT + (((size_t)ehb) * ND + d) * NN + i) = pk.u64;
        }
    float w1a = a1w[eh * ND + w * 32 + m], w1b = a1w[eh * ND + w * 32 + 16 + m];
    float w2a = a2w[eh * ND + w * 32 + m], w2b = a2w[eh * ND + w * 32 + 16 + m];
    float p1[2][4], p2[2][4];
#pragma unroll
    for (int mt = 0; mt < 2; ++mt)
#pragma unroll
        for (int r = 0; r < 4; ++r) {
            p1[mt][r] = acc[mt][0][r] * w1a + acc[mt][1][r] * w1b;
            p2[mt][r] = acc[mt][0][r] * w2a + acc[mt][1][r] * w2b;
        }
#pragma unroll
    for (int off = 8; off >= 1; off >>= 1)
#pragma unroll
        for (int mt = 0; mt < 2; ++mt)
#pragma unroll
            for (int r = 0; r < 4; ++r) {
                p1[mt][r] += __shfl_xor(p1[mt][r], off);
                p2[mt][r] += __shfl_xor(p2[mt][r], off);
            }
    __shared__ float sred[2][4][4][8];
    if (m == 0) {
#pragma unroll
        for (int mt = 0; mt < 2; ++mt)
#pragma unroll
            for (int r = 0; r < 4; ++r) {
                sred[0][w][quad][mt * 4 + r] = p1[mt][r];
                sred[1][w][quad][mt * 4 + r] = p2[mt][r];
            }
    }
    __syncthreads();
    if (t < 32) {
        int mt = t >> 4, quad2 = (t >> 2) & 3, r = t & 3;
        int c = mt * 4 + r;
        float v = sred[0][0][quad2][c] + sred[0][1][quad2][c] + sred[0][2][quad2][c] +
                  sred[0][3][quad2][c];
        s1[(size_t)ehb * NN + i0b + t] = v + a1b[eh];
    } else if (t < 64) {
        int tl = t - 32;
        int mt = tl >> 4, quad2 = (tl >> 2) & 3, r = tl & 3;
        int c = mt * 4 + r;
        float v = sred[1][0][quad2][c] + sred[1][1][quad2][c] + sred[1][2][quad2][c] +
                  sred[1][3][quad2][c];
        s2[(size_t)ehb * NN + i0b + tl] = v + a2b[eh];
    }
}

// ---------------- layer-1 filter GEMM (K=512) + s1/s2 epilogue, XCD-swizzled ----------
__global__ __launch_bounds__(256, 4) void whgemm1k(
    const unsigned short* __restrict__ state, const unsigned short* __restrict__ WT,
    unsigned short* __restrict__ WhT, const float* __restrict__ a1w,
    const float* __restrict__ a1b, const float* __restrict__ a2w,
    const float* __restrict__ a2b, float* __restrict__ s1, float* __restrict__ s2) {
    int id = blockIdx.x;
    int g = id & 7, s_ = id >> 3;
    int eh = s_ & 3;
    int row0 = ((s_ >> 2) * 8 + g) * 32;
    int t = threadIdx.x;
    int w = t >> 6, lane = t & 63;
    int m = lane & 15, quad = lane >> 4;

    f32x4 acc[2][2];
#pragma unroll
    for (int mt = 0; mt < 2; ++mt)
#pragma unroll
        for (int nt = 0; nt < 2; ++nt) acc[mt][nt] = (f32x4){0.f, 0.f, 0.f, 0.f};

    const unsigned short* Ab = state + (size_t)(row0 + m) * FIN1 + quad * 8;
    const unsigned short* Bb = WT + ((size_t)eh * ND + w * 32 + m) * FIN1 + quad * 8;
#pragma unroll 4
    for (int k0 = 0; k0 < FIN1; k0 += 32) {
        short8 a[2], b[2];
#pragma unroll
        for (int mt = 0; mt < 2; ++mt)
            a[mt] = *(const short8*)(Ab + (size_t)mt * 16 * FIN1 + k0);
#pragma unroll
        for (int nt = 0; nt < 2; ++nt)
            b[nt] = *(const short8*)(Bb + (size_t)nt * 16 * FIN1 + k0);
#pragma unroll
        for (int mt = 0; mt < 2; ++mt)
#pragma unroll
            for (int nt = 0; nt < 2; ++nt)
                acc[mt][nt] =
                    __builtin_amdgcn_mfma_f32_16x16x32_bf16(a[mt], b[nt], acc[mt][nt], 0, 0, 0);
    }
    int b_ = row0 >> 10, i0b = row0 & 1023;
    int ehb = eh * NB + b_;
#pragma unroll
    for (int mt = 0; mt < 2; ++mt)
#pragma unroll
        for (int nt = 0; nt < 2; ++nt) {
            int d = w * 32 + nt * 16 + m;
            int i = i0b + mt * 16 + quad * 4;
            union { unsigned short us[4]; unsigned long long u64; } pk;
#pragma unroll
            for (int r = 0; r < 4; ++r) pk.us[r] = f2bf(acc[mt][nt][r]);
            *(unsigned long long*)(WhT + (((size_t)ehb) * ND + d) * NN + i) = pk.u64;
        }
    float w1a = a1w[eh * ND + w * 32 + m], w1b = a1w[eh * ND + w * 32 + 16 + m];
    float w2a = a2w[eh * ND + w * 32 + m], w2b = a2w[eh * ND + w * 32 + 16 + m];
    float p1[2][4], p2[2][4];
#pragma unroll
    for (int mt = 0; mt < 2; ++mt)
#pragma unroll
        for (int r = 0; r < 4; ++r) {
            p1[mt][r] = acc[mt][0][r] * w1a + acc[mt][1][r] * w1b;
            p2[mt][r] = acc[mt][0][r] * w2a + acc[mt][1][r] * w2b;
        }
#pragma unroll
    for (int off = 8; off >= 1; off >>= 1)
#pragma unroll
        for (int mt = 0; mt < 2; ++mt)
#pragma unroll
            for (int r = 0; r < 4; ++r) {
                p1[mt][r] += __shfl_xor(p1[mt][r], off);
                p2[mt][r] += __shfl_xor(p2[mt][r], off);
            }
    __shared__ float sred[2][4][4][8];
    if (m == 0) {
#pragma unroll
        for (int mt = 0; mt < 2; ++mt)
#pragma unroll
            for (int r = 0; r < 4; ++r) {
                sred[0][w][quad][mt * 4 + r] = p1[mt][r];
                sred[1][w][quad][mt * 4 + r] = p2[mt][r];
            }
    }
    __syncthreads();
    if (t < 32) {
        int mt = t >> 4, quad2 = (t >> 2) & 3, r = t & 3;
        int c = mt * 4 + r;
        float v = sred[0][0][quad2][c] + sred[0][1][quad2][c] + sred[0][2][quad2][c] +
                  sred[0][3][quad2][c];
        s1[(size_t)ehb * NN + i0b + t] = v + a1b[eh];
    } else if (t < 64) {
        int tl = t - 32;
        int mt = tl >> 4, quad2 = (tl >> 2) & 3, r = tl & 3;
        int c = mt * 4 + r;
        float v = sred[1][0][quad2][c] + sred[1][1][quad2][c] + sred[1][2][quad2][c] +
                  sred[1][3][quad2][c];
        s2[(size_t)ehb * NN + i0b + tl] = v + a2b[eh];
    }
}

// ---------------- column sums (no-max softmax): Spart[ic][eh][b][j], float4 j-pairs ----
__global__ __launch_bounds__(256, 4) void colsumk(const float* __restrict__ edges,
                                                  const float* __restrict__ s1,
                                                  const float* __restrict__ s2,
                                                  float* __restrict__ Spart) {
    int jt = blockIdx.x, b = blockIdx.y, ic = blockIdx.z;
    int t = threadIdx.x;
    int jp = t & 31, is = t >> 5;          // j-pair, i-chunk (16 i each)
    int j = jt * 64 + jp * 2;
    __shared__ float s1L[4][128];
    for (int idx = t; idx < 512; idx += 256) {
        int eh = idx >> 7;
        s1L[eh][idx & 127] = s1[((size_t)eh * NB + b) * NN + ic * 128 + (idx & 127)];
    }
    __syncthreads();
    float s2v[4][2], acc4[4][2];
#pragma unroll
    for (int eh = 0; eh < 4; ++eh) {
        s2v[eh][0] = s2[((size_t)eh * NB + b) * NN + j];
        s2v[eh][1] = s2[((size_t)eh * NB + b) * NN + j + 1];
        acc4[eh][0] = 0.f;
        acc4[eh][1] = 0.f;
    }
    const float4* ep = (const float4*)edges +
                       (size_t)(b * NN + ic * 128 + is * 16) * (NN / 2) + jt * 32 + jp;
#pragma unroll 4
    for (int ii = 0; ii < 16; ++ii) {
        float4 ev = ep[(size_t)ii * (NN / 2)];   // (e0,e1) at j ; (e0,e1) at j+1
        float s1v = s1L[0][is * 16 + ii];        // placeholder; per-eh below
#pragma unroll
        for (int eh = 0; eh < 4; ++eh) {
            float sv = s1L[eh][is * 16 + ii];
            float x0 = sv + s2v[eh][0];
            x0 = fmaxf(x0, 0.2f * x0);
            acc4[eh][0] += __expf(x0 + (eh < 2 ? ev.x : ev.y));
            float x1 = sv + s2v[eh][1];
            x1 = fmaxf(x1, 0.2f * x1);
            acc4[eh][1] += __expf(x1 + (eh < 2 ? ev.z : ev.w));
        }
        (void)s1v;
    }
    __shared__ float red[8][4][64];  // [is][eh][jl]
#pragma unroll
    for (int eh = 0; eh < 4; ++eh) {
        red[is][eh][jp * 2] = acc4[eh][0];
        red[is][eh][jp * 2 + 1] = acc4[eh][1];
    }
    __syncthreads();
    if (t < 256) {
        int eho = t >> 6, jlo = t & 63;
        float Sv = 0.f;
#pragma unroll
        for (int isx = 0; isx < 8; ++isx) Sv += red[isx][eho][jlo];
        Spart[(((size_t)ic * EHC + eho) * NB + b) * NN + jt * 64 + jlo] = Sv;
    }
}

// ---------------- fused msg: C[d][i] = sum_j Wh[j,d]*exp(a_ij - lnS_j), MFMA ------------
// 512 threads: 8 waves each own 16 d (M) and 8 i-rows of P-compute.
__global__ __launch_bounds__(512, 4) void msgk(const float* __restrict__ edges,
                                               const unsigned short* __restrict__ WhT,
                                               const float* __restrict__ s1,
                                               const float* __restrict__ s2,
                                               const float* __restrict__ Spart,
                                               const float* __restrict__ sb,
                                               unsigned short* __restrict__ out0,
                                               float* __restrict__ out1, int mode) {
    int id = blockIdx.x;
    int b = id & 7;                 // XCD slot: 4 eh-blocks of same (itile,b) share L2
    int s_ = id >> 3;
    int eh = s_ & 3;
    int itile = s_ >> 2;
    int e = eh >> 1;
    int i0 = itile * 64;
    int t = threadIdx.x;
    int w = t >> 6, lane = t & 63;
    int n = lane & 15, quad = lane >> 4;
    int jl = t & 63, ib = w;        // P-compute: 8 rows x 1 col per thread

    __shared__ float2 stL[NN];                  // {s2, lnS} per j
    __shared__ unsigned short pA[2][64 * 72];

    int base = (eh * NB + b) * NN;
    const size_t pstr = (size_t)EHC * NB * NN;
    for (int jj = t; jj < NN; jj += 512) {
        float S = 0.f;
#pragma unroll
        for (int ic = 0; ic < 8; ++ic) S += Spart[(size_t)ic * pstr + base + jj];
        stL[jj] = make_float2(s2[base + jj], __logf(S));
    }
    float s1r[8];
    {
        const f32x4* sp = (const f32x4*)(s1 + base + i0 + ib * 8);
        f32x4 v0 = sp[0], v1 = sp[1];
#pragma unroll
        for (int r = 0; r < 4; ++r) { s1r[r] = v0[r]; s1r[r + 4] = v1[r]; }
    }

    f32x4 acc[4];
#pragma unroll
    for (int nt = 0; nt < 4; ++nt) acc[nt] = (f32x4){0.f, 0.f, 0.f, 0.f};

    // A operand: this wave's 16 d-rows (d = w*16 + n)
    const unsigned short* Ab =
        WhT + ((size_t)base * ND + (size_t)(w * 16 + n) * NN) + quad * 8;
    const float2* ep = (const float2*)edges + (size_t)(b * NN + i0 + ib * 8) * NN + jl;
    __syncthreads();  // stL ready

    float2 evA[8], evB[8];
    short8 aA[2], aB[2];

    auto loadE = [&](float2* ev, int j0) {
#pragma unroll
        for (int q = 0; q < 8; ++q) ev[q] = ep[(size_t)q * NN + j0];
    };
    auto loadA = [&](short8* av, int j0) {
#pragma unroll
        for (int kt = 0; kt < 2; ++kt)
            av[kt] = *(const short8*)(Ab + kt * 32 + j0);
    };
    auto pstep = [&](const float2* ev, const short8* av, int j0, int buf) {
        float2 stj = stL[j0 + jl];
#pragma unroll
        for (int q = 0; q < 8; ++q) {
            float edge = e ? ev[q].y : ev[q].x;
            float x = s1r[q] + stj.x;
            x = fmaxf(x, 0.2f * x);
            pA[buf][(ib * 8 + q) * 72 + jl] = f2bf(__expf(x + edge - stj.y));
        }
        __syncthreads();
#pragma unroll
        for (int kt = 0; kt < 2; ++kt) {
            short8 bv[4];
#pragma unroll
            for (int nt = 0; nt < 4; ++nt)
                bv[nt] = *(const short8*)&pA[buf][(nt * 16 + n) * 72 + kt * 32 + quad * 8];
#pragma unroll
            for (int nt = 0; nt < 4; ++nt)
                acc[nt] =
                    __builtin_amdgcn_mfma_f32_16x16x32_bf16(av[kt], bv[nt], acc[nt], 0, 0, 0);
        }
    };

    loadE(evA, 0);
    loadA(aA, 0);
    for (int sp2 = 0; sp2 < 8; ++sp2) {
        int j0 = sp2 * 128;
        loadE(evB, j0 + 64);
        loadA(aB, j0 + 64);
        pstep(evA, aA, j0, 0);
        if (sp2 < 7) {
            loadE(evA, j0 + 128);
            loadA(aA, j0 + 128);
        }
        pstep(evB, aB, j0 + 64, 1);
    }

    // epilogue: C row(quad*4+r) = d-local, col(lane&15) = i-local
    {
        int d0 = w * 16 + quad * 4;
        f32x4 sbv = *(const f32x4*)&sb[eh * ND + d0];
#pragma unroll
        for (int nt = 0; nt < 4; ++nt) {
            int i = i0 + nt * 16 + n;
            if (mode == 0) {
                union { unsigned short us[4]; unsigned long long u64; } pk;
#pragma unroll
                for (int r = 0; r < 4; ++r) pk.us[r] = f2bf(acc[nt][r] + sbv[r]);
                *(unsigned long long*)(out0 + (size_t)(b * NN + i) * FIN1 + eh * ND + d0) =
                    pk.u64;
            } else {
                f32x4 vv;
#pragma unroll
                for (int r = 0; r < 4; ++r) {
                    float v = acc[nt][r] + sbv[r];
                    vv[r] = v > 0.f ? v : expm1f(v);
                }
                *(f32x4*)(out1 + ((size_t)(eh * NB + b) * NN + i) * ND + d0) = vv;
            }
        }
    }
}

// ---------------- final: out = mean_eh(m1) @ Wout + bout (fused) ----------------
__global__ __launch_bounds__(256) void finalk(const float* __restrict__ m1,
                                              const float* __restrict__ Wout,
                                              const float* __restrict__ bout,
                                              float* __restrict__ out) {
    int row0 = blockIdx.x * 16;
    int t = threadIdx.x;
    __shared__ float sF[16 * ND];
    __shared__ float wL[ND * NO];
    const size_t str = (size_t)BN * ND;
    for (int idx = t; idx < 16 * ND; idx += 256) {
        size_t r = (size_t)row0 * ND + idx;
        sF[idx] = 0.25f * (m1[r] + m1[r + str] + m1[r + 2 * str] + m1[r + 3 * str]);
    }
    for (int idx = t; idx < ND * NO; idx += 256) wL[idx] = Wout[idx];
    __syncthreads();
    int o = t & 63;
    int rr = t >> 6;
    float bo = bout[o];
#pragma unroll
    for (int q = 0; q < 4; ++q) {
        int r = rr * 4 + q;
        float acc = 0.f;
#pragma unroll 4
        for (int d = 0; d < ND; ++d) acc += sF[r * ND + d] * wL[d * NO + o];
        out[(size_t)(row0 + r) * NO + o] = acc + bo;
    }
}

extern "C" void kernel_launch(void* const* d_in, const int* in_sizes, int n_in,
                              void* d_out, int out_size, void* d_ws, size_t ws_size,
                              hipStream_t stream) {
    const float* nodes = (const float*)d_in[0];
    const float* edges = (const float*)d_in[1];
    const float* Wemb = (const float*)d_in[2];
    const float* bemb = (const float*)d_in[3];
    const float* W0 = (const float*)d_in[4];
    const float* A1w0 = (const float*)d_in[5];
    const float* A1b0 = (const float*)d_in[6];
    const float* A2w0 = (const float*)d_in[7];
    const float* A2b0 = (const float*)d_in[8];
    const float* SB0 = (const float*)d_in[9];
    const float* W1 = (const float*)d_in[10];
    const float* A1w1 = (const float*)d_in[11];
    const float* A1b1 = (const float*)d_in[12];
    const float* A2w1 = (const float*)d_in[13];
    const float* A2b1 = (const float*)d_in[14];
    const float* SB1 = (const float*)d_in[15];
    const float* Wout = (const float*)d_in[16];
    const float* bout = (const float*)d_in[17];
    float* out = (float*)d_out;

    char* p = (char*)d_ws;
    auto alloc = [&](size_t bytes) {
        char* r = p;
        p += (bytes + 255) & ~(size_t)255;
        return r;
    };
    unsigned short* W0T = (unsigned short*)alloc((size_t)EHC * ND * ND * 2);
    unsigned short* W1T = (unsigned short*)alloc((size_t)EHC * ND * FIN1 * 2);
    unsigned short* WembT = (unsigned short*)alloc((size_t)ND * NI * 2);
    unsigned short* WhT = (unsigned short*)alloc((size_t)EHC * BN * ND * 2);
    unsigned short* state1 = (unsigned short*)alloc((size_t)BN * FIN1 * 2);
    float* s1b = (float*)alloc((size_t)EHC * BN * 4);
    float* s2b = (float*)alloc((size_t)EHC * BN * 4);
    float* Spart = (float*)alloc((size_t)8 * EHC * BN * 4);
    float* m1 = (float*)alloc((size_t)EHC * BN * ND * 4);

    prepTk<<<1312, 256, 0, stream>>>(W0, W1, Wemb, W0T, W1T, WembT);
    // layer 0 (embed fused into filter GEMM)
    embwh0k<<<1024, 256, 0, stream>>>(nodes, WembT, bemb, W0T, WhT, A1w0, A1b0, A2w0, A2b0,
                                      s1b, s2b);
    colsumk<<<dim3(NN / 64, NB, 8), 256, 0, stream>>>(edges, s1b, s2b, Spart);
    msgk<<<512, 512, 0, stream>>>(edges, WhT, s1b, s2b, Spart, SB0, state1, m1, 0);
    // layer 1
    whgemm1k<<<1024, 256, 0, stream>>>(state1, W1T, WhT, A1w1, A1b1, A2w1, A2b1, s1b, s2b);
    colsumk<<<dim3(NN / 64, NB, 8), 256, 0, stream>>>(edges, s1b, s2b, Spart);
    msgk<<<512, 512, 0, stream>>>(edges, WhT, s1b, s2b, Spart, SB1, state1, m1, 1);
    // head
    finalk<<<BN / 16, 256, 0, stream>>>(m1, Wout, bout, out);
}